// Round 1
// baseline (354.413 us; speedup 1.0000x reference)
//
#include <hip/hip_runtime.h>
#include <stdint.h>

// GhostAttention on MI355X (gfx950). B=2, T=2048, C=2048, H=16, hd=128.
// All-fp16 pipeline: convert (single launch) -> fused QKV GEMM -> causal
// relu-attention (linear normalizer) -> out GEMM (fp32 out).
//
// R6: GEMMs rewritten as 512-thread BM=128 x BN=256 x BK=64 with a 3-deep
// LDS ring (144 KB) and counted-vmcnt pipeline (T3+T4): compute tile t from
// buf[t%3] while t+1 is resident and t+2's 6 global_load_lds are in flight;
// tile-end s_waitcnt vmcnt(6) + raw s_barrier (NO vmcnt(0) drain in loop).
// 2 phases/tile (kk=0/1): 8 ds_read_b128 || 3 gload_lds || 16 MFMA with
// setprio(1) (T5). Grid: QKV 768 blocks = 3 exact CU-waves; out 256 = 1.
// Bijective XCD swizzle + 8-row A-supertile for L2 locality.

typedef unsigned short u16;
typedef _Float16 f16x8 __attribute__((ext_vector_type(8)));
typedef float floatx4 __attribute__((ext_vector_type(4)));
typedef unsigned short ushort8_t __attribute__((ext_vector_type(8)));

__device__ __forceinline__ u16 f2h(float f) {
  _Float16 h = (_Float16)f;                  // v_cvt_f16_f32, RNE
  return __builtin_bit_cast(u16, h);
}
__device__ __forceinline__ f16x8 ld_frag(const u16* p) {
  return __builtin_bit_cast(f16x8, *(const ushort8_t*)p);
}

// XOR-swizzled LDS offset: row length R elems (R%8==0), cprMask = R/8-1.
__device__ __forceinline__ int swz(int row, int col, int R, int cprMask) {
  int chunk = ((col >> 3) ^ row) & cprMask;
  return row * R + chunk * 8 + (col & 7);
}

__device__ __forceinline__ void async_copy16(const void* g, void* l) {
  __builtin_amdgcn_global_load_lds(
      (const __attribute__((address_space(1))) void*)g,
      (__attribute__((address_space(3))) void*)l, 16, 0, 0);
}

// Stage instructions [I0,I1) of a (rows x R fp16) tile (row stride grs) into
// swizzled LDS; NTHR threads, 16B per thread per instruction.
template<int R, int I0, int I1, int NTHR>
__device__ __forceinline__ void stage_part(const u16* g, size_t grs, u16* lds, int tid) {
  constexpr int CPR = R / 8;
  #pragma unroll
  for (int i = I0; i < I1; ++i) {
    int f = tid + i * NTHR;
    int row = f / CPR;
    int sc = f & (CPR - 1);
    int c = sc ^ (row & (CPR - 1));
    async_copy16(g + (size_t)row * grs + c * 8, (char*)lds + f * 16);
  }
}

// 256-thread version (attention kernel).
template<int R, int NINST>
__device__ __forceinline__ void stage_swz(const u16* g, size_t grs, u16* lds, int tid) {
  stage_part<R, 0, NINST, 256>(g, grs, lds, tid);
}

// ---------------------------------------------------------------- converts
// One launch for all five fp32->fp16 conversions. Regions in float4 groups:
// x = 2^21 groups, each W = 2^20 groups.
__global__ void convert_all(const float* __restrict__ x,
                            const float* __restrict__ Wq, const float* __restrict__ Wk,
                            const float* __restrict__ Wv, const float* __restrict__ Wo,
                            u16* __restrict__ xb, u16* __restrict__ wqb, u16* __restrict__ wkb,
                            u16* __restrict__ wvb, u16* __restrict__ wob) {
  const int gi = blockIdx.x * 256 + threadIdx.x;   // float4-group index
  const float* src;
  u16* dst;
  int off;
  if (gi < (1 << 21)) {
    src = x; dst = xb; off = gi;
  } else {
    const int j = gi - (1 << 21);
    const int wsel = j >> 20;
    off = j & ((1 << 20) - 1);
    src = (wsel == 0) ? Wq : (wsel == 1) ? Wk : (wsel == 2) ? Wv : Wo;
    dst = (wsel == 0) ? wqb : (wsel == 1) ? wkb : (wsel == 2) ? wvb : wob;
  }
  float4 v = ((const float4*)src)[off];
  ushort4 o;
  o.x = f2h(v.x); o.y = f2h(v.y); o.z = f2h(v.z); o.w = f2h(v.w);
  ((ushort4*)dst)[off] = o;
}

// ---------------------------------------------------------------- GEMM (B^T)
// C = A[M,K] @ B[N,K]^T, fp16 in, fp32 accum. BM=128, BN=256, BK=64,
// 512 threads (8 waves, 2x4), wave tile 64x64. 3-buffer LDS ring, counted
// vmcnt(6) pipeline (6 gload_lds / thread / tile).
// MODE 1: fp32 row-major C0[M,N]   (final projection)
// MODE 3: fused QKV: N=6144; sel = bn0/2048 -> Q (C0) / K (C1) head-major
//         [B,H,T,128]; V (C2) written TRANSPOSED [B,H,128,T] via LDS.
template<int MODE>
__global__ __launch_bounds__(512, 2) void gemm8p(
    const u16* __restrict__ A,
    const u16* __restrict__ B0, const u16* __restrict__ B1, const u16* __restrict__ B2,
    void* __restrict__ C0, void* __restrict__ C1, void* __restrict__ C2,
    const int M, const int N, const int K)
{
  // 3 x (A 128x64 | B 256x64) fp16 = 3 x 24576 u16 = 144 KB
  __shared__ __align__(16) u16 smem[3 * 24576];
  const int tid = threadIdx.x;
  const int w = tid >> 6, lane = tid & 63, lr = lane & 15, lq = lane >> 4;
  const int wr = w >> 2, wc = w & 3;            // 2(m) x 4(n) wave grid

  // XCD-bijective swizzle (nwg % 8 == 0 for both grids) + 8-row A-supertile.
  const int nbx = N >> 8, nby = M >> 7;
  const int nwg = nbx * nby;
  int wg = blockIdx.x;
  wg = (wg & 7) * (nwg >> 3) + (wg >> 3);
  const int rg = wg % (nbx * 8);
  const int by = (wg / (nbx * 8)) * 8 + (rg & 7);
  const int bx = rg >> 3;
  const int bn0 = bx << 8, bm0 = by << 7;

  const u16* Ab = A + (size_t)bm0 * K;
  const int sel = bn0 >> 11;                    // which output (MODE 3)
  const u16* Bb;
  if (MODE == 3) {
    const u16* Bsel = (sel == 0) ? B0 : (sel == 1) ? B1 : B2;
    Bb = Bsel + (size_t)(bn0 & 2047) * K;
  } else {
    Bb = B0 + (size_t)bn0 * K;
  }

  floatx4 acc[4][4] = {};
  const int NT = K >> 6;                        // 32 K-tiles

  // prologue: stage tiles 0 and 1 into buffers 0,1 (6 loads each)
  stage_part<64, 0, 2, 512>(Ab,      K, smem,                 tid);
  stage_part<64, 0, 4, 512>(Bb,      K, smem + 8192,          tid);
  stage_part<64, 0, 2, 512>(Ab + 64, K, smem + 24576,         tid);
  stage_part<64, 0, 4, 512>(Bb + 64, K, smem + 24576 + 8192,  tid);
  asm volatile("s_waitcnt vmcnt(6)" ::: "memory");   // tile 0 resident
  asm volatile("s_barrier" ::: "memory");

  int cur = 0, nx2 = 2;
  for (int t = 0; t < NT; ++t) {
    u16* As = smem + cur * 24576;
    u16* Bs = As + 8192;
    u16* Ld = smem + nx2 * 24576;
    const int kg = (t + 2) << 6;
    const bool st = (t + 2) < NT;

    f16x8 af[4], bf[4];
    // ---- phase 0 (kk = 0): 8 ds_read || 3 gload_lds || 16 MFMA
    #pragma unroll
    for (int mt = 0; mt < 4; ++mt)
      af[mt] = ld_frag(&As[swz(wr * 64 + mt * 16 + lr, lq * 8, 64, 7)]);
    #pragma unroll
    for (int nt = 0; nt < 4; ++nt)
      bf[nt] = ld_frag(&Bs[swz(wc * 64 + nt * 16 + lr, lq * 8, 64, 7)]);
    if (st) {
      stage_part<64, 0, 2, 512>(Ab + kg, K, Ld, tid);         // A tile (2)
      stage_part<64, 0, 1, 512>(Bb + kg, K, Ld + 8192, tid);  // B rows 0-63
    }
    __builtin_amdgcn_s_setprio(1);
    #pragma unroll
    for (int mt = 0; mt < 4; ++mt)
      #pragma unroll
      for (int nt = 0; nt < 4; ++nt)
        acc[mt][nt] = __builtin_amdgcn_mfma_f32_16x16x32_f16(af[mt], bf[nt], acc[mt][nt], 0, 0, 0);
    __builtin_amdgcn_s_setprio(0);
    asm volatile("s_barrier" ::: "memory");

    // ---- phase 1 (kk = 1)
    #pragma unroll
    for (int mt = 0; mt < 4; ++mt)
      af[mt] = ld_frag(&As[swz(wr * 64 + mt * 16 + lr, 32 + lq * 8, 64, 7)]);
    #pragma unroll
    for (int nt = 0; nt < 4; ++nt)
      bf[nt] = ld_frag(&Bs[swz(wc * 64 + nt * 16 + lr, 32 + lq * 8, 64, 7)]);
    if (st)
      stage_part<64, 1, 4, 512>(Bb + kg, K, Ld + 8192, tid);  // B rows 64-255
    __builtin_amdgcn_s_setprio(1);
    #pragma unroll
    for (int mt = 0; mt < 4; ++mt)
      #pragma unroll
      for (int nt = 0; nt < 4; ++nt)
        acc[mt][nt] = __builtin_amdgcn_mfma_f32_16x16x32_f16(af[mt], bf[nt], acc[mt][nt], 0, 0, 0);
    __builtin_amdgcn_s_setprio(0);

    // tile end: t+1's loads are strictly older than the 6 just issued ->
    // vmcnt(6) proves t+1 fully resident. Last two tiles issue nothing: drain.
    if (st) asm volatile("s_waitcnt vmcnt(6)" ::: "memory");
    else    asm volatile("s_waitcnt vmcnt(0)" ::: "memory");
    asm volatile("s_barrier" ::: "memory");

    cur = (cur == 2) ? 0 : cur + 1;
    nx2 = (nx2 == 2) ? 0 : nx2 + 1;
  }

  // epilogue: C/D layout col=lane&15, row=(lane>>4)*4+reg
  if (MODE == 3 && sel == 2) {
    // V: transpose 128(t) x 256(d, 2 heads) tile through LDS,
    // write Vt [BH,128,T] coalesced. (final loop barrier already passed)
    #pragma unroll
    for (int mt = 0; mt < 4; ++mt) {
      #pragma unroll
      for (int nt = 0; nt < 4; ++nt) {
        #pragma unroll
        for (int r = 0; r < 4; ++r) {
          const int tl = wr * 64 + mt * 16 + lq * 4 + r;   // local t
          const int d  = wc * 64 + nt * 16 + lr;           // local n (0..255)
          smem[swz(d, tl, 128, 15)] = f2h(acc[mt][nt][r]);
        }
      }
    }
    __syncthreads();
    const int bb = bm0 >> 11, t0 = bm0 & 2047;
    const int n0 = bn0 & 2047;
    #pragma unroll
    for (int i = 0; i < 8; ++i) {
      const int f = tid + i * 512;           // chunk id 0..4095
      const int row = f >> 4;                // local d (0..255)
      const int cc = f & 15;                 // stored chunk
      const int c = cc ^ (row & 15);         // logical t-chunk
      ushort8_t v = *(const ushort8_t*)&smem[row * 128 + cc * 8];
      const int h = (n0 + row) >> 7, d = (n0 + row) & 127;
      *(ushort8_t*)((u16*)C2 + ((size_t)(bb * 16 + h) * 128 + d) * 2048 + t0 + c * 8) = v;
    }
  } else if (MODE == 3) {
    #pragma unroll
    for (int mt = 0; mt < 4; ++mt) {
      #pragma unroll
      for (int nt = 0; nt < 4; ++nt) {
        #pragma unroll
        for (int r = 0; r < 4; ++r) {
          const int m = bm0 + wr * 64 + mt * 16 + lq * 4 + r;
          const int n = bn0 + wc * 64 + nt * 16 + lr;
          const int nn = n & 2047;
          const int bb = m >> 11, tt = m & 2047, h = nn >> 7, d = nn & 127;
          const size_t idx = (((size_t)(bb * 16 + h) * 2048) + tt) * 128 + d;
          u16* Cs = (sel == 0) ? (u16*)C0 : (u16*)C1;
          Cs[idx] = f2h(acc[mt][nt][r]);
        }
      }
    }
  } else {
    #pragma unroll
    for (int mt = 0; mt < 4; ++mt) {
      #pragma unroll
      for (int nt = 0; nt < 4; ++nt) {
        #pragma unroll
        for (int r = 0; r < 4; ++r) {
          const int m = bm0 + wr * 64 + mt * 16 + lq * 4 + r;
          const int n = bn0 + wc * 64 + nt * 16 + lr;
          ((float*)C0)[(size_t)m * N + n] = acc[mt][nt][r];
        }
      }
    }
  }
}

// ---------------------------------------------------------------- attention
// Block: one (bh, 128-row q-tile). k-tiles of 64, K/V double-buffered:
// per iter [B1: staging visible + prev PV fenced; issue prefetch; QK; P-write;
// B2: Ps visible (drains prefetch after QK overlap); PV]. 2 barriers/iter.
// QK wave-split 64q x 32k: each kf LDS read feeds 4 MFMAs.
// LDS 80 KB: Ks0|Ks1|Vts0|Vts1|Ps -> 2 blocks/CU.
__global__ __launch_bounds__(256, 2) void attn_kernel(
    const u16* __restrict__ Qh, const u16* __restrict__ Kh,
    const u16* __restrict__ Vt, u16* __restrict__ Ob)
{
  __shared__ __align__(16) u16 smem[40960];   // 80 KB
  const int tid = threadIdx.x;
  const int w = tid >> 6, lane = tid & 63, lr = lane & 15, lq = lane >> 4;
  const int bh = blockIdx.x;
  const int y = blockIdx.y;
  // complementary interleave: blocks y and y+8 have qt summing to 15 ->
  // uniform k-iter load across CUs
  const int qt = (y < 8) ? (15 - y) : (y - 8);
  const int q0 = qt * 128;
  const size_t bhT = (size_t)bh * 2048;
  const u16* Vtb = Vt + (size_t)bh * 128 * 2048;

  // Q tile 128x128 staged through smem[0..16383] -> registers (64 q-rows/wave)
  stage_swz<128, 8>(Qh + (bhT + q0) * 128, 128, smem, tid);
  __syncthreads();
  const int mq0 = (w >> 1) * 64, nk0 = (w & 1) * 32;
  f16x8 qf[4][4];
  #pragma unroll
  for (int mt = 0; mt < 4; ++mt)
    #pragma unroll
    for (int kk = 0; kk < 4; ++kk)
      qf[mt][kk] = ld_frag(&smem[swz(mq0 + mt * 16 + lr, kk * 32 + lq * 8, 128, 15)]);
  __syncthreads();                            // Q reads done before K staging

  // prefetch first K/V tile into buffer 0
  stage_swz<128, 4>(Kh + (bhT + 0) * 128, 128, smem, tid);
  stage_swz<64, 4>(Vtb + 0, 2048, smem + 16384, tid);

  floatx4 oacc[2][8] = {};
  floatx4 den[2] = {};
  const ushort8_t onesu = {0x3C00, 0x3C00, 0x3C00, 0x3C00, 0x3C00, 0x3C00, 0x3C00, 0x3C00};
  const f16x8 ones = __builtin_bit_cast(f16x8, onesu);
  const float scale = 0.08838834764831845f;   // 1/sqrt(128)

  const int kend = q0 + 128;
  int buf = 0;
  for (int k0 = 0; k0 < kend; k0 += 64) {
    u16* Ks  = smem + buf * 8192;             // [64 k][128 d] swz cpr16
    u16* Vts = smem + 16384 + buf * 8192;     // [128 d][64 k] swz cpr8
    u16* Ps  = smem + 32768;                  // [128 q][64 k] swz cpr8
    __syncthreads();                          // B1: cur staging visible; prev PV fenced

    if (k0 + 64 < kend) {                     // issue prefetch of next tile (async)
      stage_swz<128, 4>(Kh + (bhT + k0 + 64) * 128, 128, smem + (buf ^ 1) * 8192, tid);
      stage_swz<64, 4>(Vtb + k0 + 64, 2048, smem + 16384 + (buf ^ 1) * 8192, tid);
    }

    // S = Q K^T : 64 q-rows x 32 keys per wave (kf read feeds 4 MFMAs)
    floatx4 s[4][2] = {};
    #pragma unroll
    for (int kk = 0; kk < 4; ++kk) {
      f16x8 kf[2];
      #pragma unroll
      for (int nt = 0; nt < 2; ++nt)
        kf[nt] = ld_frag(&Ks[swz(nk0 + nt * 16 + lr, kk * 32 + lq * 8, 128, 15)]);
      #pragma unroll
      for (int mt = 0; mt < 4; ++mt)
        #pragma unroll
        for (int nt = 0; nt < 2; ++nt)
          s[mt][nt] = __builtin_amdgcn_mfma_f32_16x16x32_f16(qf[mt][kk], kf[nt], s[mt][nt], 0, 0, 0);
    }

    // P = relu(S*scale + 0.1) -> Ps; causal mask only on diagonal-band tiles
    if (k0 < q0) {                            // interior: no mask needed
      #pragma unroll
      for (int mt = 0; mt < 4; ++mt) {
        const int rb = mq0 + mt * 16 + lq * 4;
        #pragma unroll
        for (int nt = 0; nt < 2; ++nt) {
          const int col = nk0 + nt * 16 + lr;
          #pragma unroll
          for (int r = 0; r < 4; ++r)
            Ps[swz(rb + r, col, 64, 7)] = f2h(fmaxf(s[mt][nt][r] * scale + 0.1f, 0.0f));
        }
      }
    } else {
      #pragma unroll
      for (int mt = 0; mt < 4; ++mt) {
        const int rb = mq0 + mt * 16 + lq * 4;
        #pragma unroll
        for (int nt = 0; nt < 2; ++nt) {
          const int col = nk0 + nt * 16 + lr;
          const int kg = k0 + col;
          #pragma unroll
          for (int r = 0; r < 4; ++r) {
            float v = fmaxf(s[mt][nt][r] * scale + 0.1f, 0.0f);
            v = (kg <= q0 + rb + r) ? v : 0.0f;
            Ps[swz(rb + r, col, 64, 7)] = f2h(v);
          }
        }
      }
    }
    __syncthreads();                          // B2: Ps visible

    // O += P @ Vt^T ; den += P @ 1   (wave w: q rows w*32..w*32+31, all d)
    #pragma unroll
    for (int kk = 0; kk < 2; ++kk) {
      f16x8 pf[2];
      #pragma unroll
      for (int mt = 0; mt < 2; ++mt)
        pf[mt] = ld_frag(&Ps[swz(w * 32 + mt * 16 + lr, kk * 32 + lq * 8, 64, 7)]);
      #pragma unroll
      for (int mt = 0; mt < 2; ++mt)
        den[mt] = __builtin_amdgcn_mfma_f32_16x16x32_f16(pf[mt], ones, den[mt], 0, 0, 0);
      #pragma unroll
      for (int dt = 0; dt < 8; ++dt) {
        f16x8 vf = ld_frag(&Vts[swz(dt * 16 + lr, kk * 32 + lq * 8, 64, 7)]);
        #pragma unroll
        for (int mt = 0; mt < 2; ++mt)
          oacc[mt][dt] = __builtin_amdgcn_mfma_f32_16x16x32_f16(pf[mt], vf, oacc[mt][dt], 0, 0, 0);
      }
    }
    buf ^= 1;
  }

  // epilogue: Ob [B*T, 2048] fp16 (row = b*2048 + t, col = h*128 + d)
  const int b = bh >> 4, h = bh & 15;
  #pragma unroll
  for (int mt = 0; mt < 2; ++mt) {
    #pragma unroll
    for (int r = 0; r < 4; ++r) {
      const int qrow = w * 32 + mt * 16 + lq * 4 + r;
      const float inv = 1.0f / (den[mt][r] + 1e-6f);
      u16* dst = Ob + ((size_t)(b * 2048 + q0 + qrow)) * 2048 + h * 128;
      #pragma unroll
      for (int dt = 0; dt < 8; ++dt)
        dst[dt * 16 + lr] = f2h(oacc[mt][dt][r] * inv);
    }
  }
}

// ---------------------------------------------------------------- launch
extern "C" void kernel_launch(void* const* d_in, const int* in_sizes, int n_in,
                              void* d_out, int out_size, void* d_ws, size_t ws_size,
                              hipStream_t stream) {
  const float* x  = (const float*)d_in[0];
  const float* Wq = (const float*)d_in[1];
  const float* Wk = (const float*)d_in[2];
  const float* Wv = (const float*)d_in[3];
  const float* Wo = (const float*)d_in[4];
  float* out = (float*)d_out;

  const size_t MB = 1024 * 1024;
  char* ws = (char*)d_ws;
  // workspace (96 MB). Ob aliases xb (dead after QKV GEMM).
  u16* xb  = (u16*)(ws);               // 16 MB [4096,2048] fp16 (later Ob)
  u16* Wqb = (u16*)(ws + 16 * MB);     //  8 MB each
  u16* Wkb = (u16*)(ws + 24 * MB);
  u16* Wvb = (u16*)(ws + 32 * MB);
  u16* Wob = (u16*)(ws + 40 * MB);
  u16* Qh  = (u16*)(ws + 48 * MB);     // 16 MB [BH,T,128]
  u16* Kh  = (u16*)(ws + 64 * MB);     // 16 MB
  u16* Vt  = (u16*)(ws + 80 * MB);     // 16 MB [BH,128,T]
  u16* Ob  = xb;

  // all converts in one launch: (2^21 + 4*2^20) float4 groups / 256 threads
  convert_all<<<24576, 256, 0, stream>>>(x, Wq, Wk, Wv, Wo, xb, Wqb, Wkb, Wvb, Wob);

  // fused QKV: N = 6144; V written pre-transposed. 768 blocks = 3 CU-waves.
  gemm8p<3><<<dim3(768), 512, 0, stream>>>(
      xb, Wqb, Wkb, Wvb, (void*)Qh, (void*)Kh, (void*)Vt, 4096, 6144, 2048);

  attn_kernel<<<dim3(32, 16), 256, 0, stream>>>(Qh, Kh, Vt, Ob);

  // out projection: 256 blocks = exactly 1 CU-wave.
  gemm8p<1><<<dim3(256), 512, 0, stream>>>(
      Ob, Wob, nullptr, nullptr, (void*)out, nullptr, nullptr, 4096, 2048, 2048);
}

// Round 2
// 352.622 us; speedup vs baseline: 1.0051x; 1.0051x over previous
//
#include <hip/hip_runtime.h>
#include <stdint.h>

// GhostAttention on MI355X (gfx950). B=2, T=2048, C=2048, H=16, hd=128.
// All-fp16 pipeline: convert (single launch) -> fused QKV GEMM -> causal
// relu-attention (linear normalizer) -> out GEMM (fp32 out).
//
// R7: post-mortem of R6 (counted-vmcnt 3-ring, 64x64 wave tiles) showed the
// binding limit is the LDS ds_read stream, not the global-load drain:
// 64x64 wave tile = 2.0 MFMA per ds_read_b128 -> LDS cycles >= MFMA cycles,
// and per-phase lockstep barriers serialized the two. Fix: keep R5's proven
// stage->sync->compute loop (multi-block TLP provides overlap) but widen to
// BM=128 x BN=256 with 2x2 waves of 64x128 tiles: 12 ds_reads feed 32 MFMAs
// (AI 2.67). LDS 48 KB -> 2 blocks/CU. bf streamed to bound VGPR.
// attn: s_setprio(1) around MFMA clusters (T5).

typedef unsigned short u16;
typedef _Float16 f16x8 __attribute__((ext_vector_type(8)));
typedef float floatx4 __attribute__((ext_vector_type(4)));
typedef unsigned short ushort8_t __attribute__((ext_vector_type(8)));

__device__ __forceinline__ u16 f2h(float f) {
  _Float16 h = (_Float16)f;                  // v_cvt_f16_f32, RNE
  return __builtin_bit_cast(u16, h);
}
__device__ __forceinline__ f16x8 ld_frag(const u16* p) {
  return __builtin_bit_cast(f16x8, *(const ushort8_t*)p);
}

// XOR-swizzled LDS offset: row length R elems (R%8==0), cprMask = R/8-1.
__device__ __forceinline__ int swz(int row, int col, int R, int cprMask) {
  int chunk = ((col >> 3) ^ row) & cprMask;
  return row * R + chunk * 8 + (col & 7);
}

__device__ __forceinline__ void async_copy16(const void* g, void* l) {
  __builtin_amdgcn_global_load_lds(
      (const __attribute__((address_space(1))) void*)g,
      (__attribute__((address_space(3))) void*)l, 16, 0, 0);
}

// Stage instructions [I0,I1) of a (rows x R fp16) tile (row stride grs) into
// swizzled LDS; NTHR threads, 16B per thread per instruction.
template<int R, int I0, int I1, int NTHR>
__device__ __forceinline__ void stage_part(const u16* g, size_t grs, u16* lds, int tid) {
  constexpr int CPR = R / 8;
  #pragma unroll
  for (int i = I0; i < I1; ++i) {
    int f = tid + i * NTHR;
    int row = f / CPR;
    int sc = f & (CPR - 1);
    int c = sc ^ (row & (CPR - 1));
    async_copy16(g + (size_t)row * grs + c * 8, (char*)lds + f * 16);
  }
}

// 256-thread version.
template<int R, int NINST>
__device__ __forceinline__ void stage_swz(const u16* g, size_t grs, u16* lds, int tid) {
  stage_part<R, 0, NINST, 256>(g, grs, lds, tid);
}

// ---------------------------------------------------------------- converts
// One launch for all five fp32->fp16 conversions. Regions in float4 groups:
// x = 2^21 groups, each W = 2^20 groups.
__global__ void convert_all(const float* __restrict__ x,
                            const float* __restrict__ Wq, const float* __restrict__ Wk,
                            const float* __restrict__ Wv, const float* __restrict__ Wo,
                            u16* __restrict__ xb, u16* __restrict__ wqb, u16* __restrict__ wkb,
                            u16* __restrict__ wvb, u16* __restrict__ wob) {
  const int gi = blockIdx.x * 256 + threadIdx.x;   // float4-group index
  const float* src;
  u16* dst;
  int off;
  if (gi < (1 << 21)) {
    src = x; dst = xb; off = gi;
  } else {
    const int j = gi - (1 << 21);
    const int wsel = j >> 20;
    off = j & ((1 << 20) - 1);
    src = (wsel == 0) ? Wq : (wsel == 1) ? Wk : (wsel == 2) ? Wv : Wo;
    dst = (wsel == 0) ? wqb : (wsel == 1) ? wkb : (wsel == 2) ? wvb : wob;
  }
  float4 v = ((const float4*)src)[off];
  ushort4 o;
  o.x = f2h(v.x); o.y = f2h(v.y); o.z = f2h(v.z); o.w = f2h(v.w);
  ((ushort4*)dst)[off] = o;
}

// ---------------------------------------------------------------- GEMM (B^T)
// C = A[M,K] @ B[N,K]^T, fp16 in, fp32 accum. BM=128, BN=256, BK=64,
// 256 threads (4 waves, 2x2), wave tile 64(m) x 128(n): per kk, 4 af + 8 bf
// ds_read_b128 feed 32 MFMAs (AI 2.67). Single-buffer stage->sync->compute
// (R5 structure; overlap from 2 blocks/CU). LDS 48 KB.
// MODE 1: fp32 row-major C0[M,N]   (final projection)
// MODE 3: fused QKV: N=6144; sel = bn0/2048 -> Q (C0) / K (C1) head-major
//         [B,H,T,128]; V (C2) written TRANSPOSED [B,H,128,T] via LDS
//         (two 128x128 passes).
template<int MODE>
__global__ __launch_bounds__(256, 2) void gemm_wide(
    const u16* __restrict__ A,
    const u16* __restrict__ B0, const u16* __restrict__ B1, const u16* __restrict__ B2,
    void* __restrict__ C0, void* __restrict__ C1, void* __restrict__ C2,
    const int M, const int N, const int K)
{
  __shared__ __align__(16) u16 smem[128 * 64 + 256 * 64];   // As | Bs, 48 KB
  u16* As = smem;
  u16* Bs = smem + 128 * 64;
  const int tid = threadIdx.x;
  const int w = tid >> 6, lane = tid & 63, lr = lane & 15, lq = lane >> 4;
  const int wm = (w >> 1) * 64;                 // wave m-offset (64 rows)
  const int wn = (w & 1) * 128;                 // wave n-offset (128 cols)

  // XCD-bijective swizzle (nwg % 8 == 0 for both grids) + 8-row A-supertile.
  const int nbx = N >> 8, nby = M >> 7;
  const int nwg = nbx * nby;
  int wg = blockIdx.x;
  wg = (wg & 7) * (nwg >> 3) + (wg >> 3);
  const int rg = wg % (nbx * 8);
  const int by = (wg / (nbx * 8)) * 8 + (rg & 7);
  const int bx = rg >> 3;
  const int bn0 = bx << 8, bm0 = by << 7;

  const u16* Ab = A + (size_t)bm0 * K;
  const int sel = bn0 >> 11;                    // which output (MODE 3)
  const u16* Bb;
  if (MODE == 3) {
    const u16* Bsel = (sel == 0) ? B0 : (sel == 1) ? B1 : B2;
    Bb = Bsel + (size_t)(bn0 & 2047) * K;
  } else {
    Bb = B0 + (size_t)bn0 * K;
  }

  floatx4 acc[4][8] = {};                       // 128 VGPR accumulator

  for (int k0 = 0; k0 < K; k0 += 64) {
    __syncthreads();
    stage_part<64, 0, 4, 256>(Ab + k0, K, As, tid);   // A 128x64
    stage_part<64, 0, 8, 256>(Bb + k0, K, Bs, tid);   // B 256x64
    __syncthreads();                            // drains vmcnt(0): tile resident
    #pragma unroll
    for (int kk = 0; kk < 2; ++kk) {
      f16x8 af[4];
      #pragma unroll
      for (int mt = 0; mt < 4; ++mt)
        af[mt] = ld_frag(&As[swz(wm + mt * 16 + lr, kk * 32 + lq * 8, 64, 7)]);
      #pragma unroll
      for (int nt = 0; nt < 8; ++nt) {          // bf streamed: 1 live at a time
        f16x8 bf = ld_frag(&Bs[swz(wn + nt * 16 + lr, kk * 32 + lq * 8, 64, 7)]);
        #pragma unroll
        for (int mt = 0; mt < 4; ++mt)
          acc[mt][nt] = __builtin_amdgcn_mfma_f32_16x16x32_f16(af[mt], bf, acc[mt][nt], 0, 0, 0);
      }
    }
  }

  // epilogue: C/D layout col=lane&15, row=(lane>>4)*4+reg
  if (MODE == 3 && sel == 2) {
    // V: transpose 128(t) x 256(d, 2 heads) via two 128x128 LDS passes,
    // write Vt [BH,128,T] coalesced.
    const int bb = bm0 >> 11, t0 = bm0 & 2047;
    const int n0 = bn0 & 2047;
    #pragma unroll
    for (int p = 0; p < 2; ++p) {
      __syncthreads();                          // guard smem reuse
      if ((w & 1) == p) {                       // waves owning this d-half
        #pragma unroll
        for (int mt = 0; mt < 4; ++mt) {
          #pragma unroll
          for (int nt = 0; nt < 8; ++nt) {
            #pragma unroll
            for (int r = 0; r < 4; ++r) {
              const int tl = wm + mt * 16 + lq * 4 + r;   // local t (0..127)
              const int dl = nt * 16 + lr;                // local d (0..127)
              smem[swz(dl, tl, 128, 15)] = f2h(acc[mt][nt][r]);
            }
          }
        }
      }
      __syncthreads();
      const int h = (n0 >> 7) + p;
      u16* base = (u16*)C2 + ((size_t)(bb * 16 + h) * 128) * 2048 + t0;
      #pragma unroll
      for (int i = 0; i < 8; ++i) {
        const int f = tid + i * 256;           // chunk id 0..2047
        const int row = f >> 4;                // local d
        const int cc = f & 15;                 // stored chunk
        const int c = cc ^ (row & 15);         // logical t-chunk
        ushort8_t v = *(const ushort8_t*)&smem[row * 128 + cc * 8];
        *(ushort8_t*)(base + (size_t)row * 2048 + c * 8) = v;
      }
    }
  } else if (MODE == 3) {
    u16* Cs = (sel == 0) ? (u16*)C0 : (u16*)C1;
    #pragma unroll
    for (int mt = 0; mt < 4; ++mt) {
      #pragma unroll
      for (int nt = 0; nt < 8; ++nt) {
        #pragma unroll
        for (int r = 0; r < 4; ++r) {
          const int m = bm0 + wm + mt * 16 + lq * 4 + r;
          const int nn = (bn0 & 2047) + wn + nt * 16 + lr;
          const int bb = m >> 11, tt = m & 2047, h = nn >> 7, d = nn & 127;
          const size_t idx = (((size_t)(bb * 16 + h) * 2048) + tt) * 128 + d;
          Cs[idx] = f2h(acc[mt][nt][r]);
        }
      }
    }
  } else {
    #pragma unroll
    for (int mt = 0; mt < 4; ++mt) {
      #pragma unroll
      for (int nt = 0; nt < 8; ++nt) {
        #pragma unroll
        for (int r = 0; r < 4; ++r) {
          const int m = bm0 + wm + mt * 16 + lq * 4 + r;
          const int n = bn0 + wn + nt * 16 + lr;
          ((float*)C0)[(size_t)m * N + n] = acc[mt][nt][r];
        }
      }
    }
  }
}

// ---------------------------------------------------------------- attention
// Block: one (bh, 128-row q-tile). k-tiles of 64, K/V double-buffered:
// per iter [B1: staging visible + prev PV fenced; issue prefetch; QK; P-write;
// B2: Ps visible (drains prefetch after QK overlap); PV]. 2 barriers/iter.
// QK wave-split 64q x 32k: each kf LDS read feeds 4 MFMAs.
// LDS 80 KB: Ks0|Ks1|Vts0|Vts1|Ps -> 2 blocks/CU.
// R7: s_setprio(1) around MFMA clusters (T5, m191: +4-7% on attn).
__global__ __launch_bounds__(256, 2) void attn_kernel(
    const u16* __restrict__ Qh, const u16* __restrict__ Kh,
    const u16* __restrict__ Vt, u16* __restrict__ Ob)
{
  __shared__ __align__(16) u16 smem[40960];   // 80 KB
  const int tid = threadIdx.x;
  const int w = tid >> 6, lane = tid & 63, lr = lane & 15, lq = lane >> 4;
  const int bh = blockIdx.x;
  const int y = blockIdx.y;
  // complementary interleave: blocks y and y+8 have qt summing to 15 ->
  // uniform k-iter load across CUs
  const int qt = (y < 8) ? (15 - y) : (y - 8);
  const int q0 = qt * 128;
  const size_t bhT = (size_t)bh * 2048;
  const u16* Vtb = Vt + (size_t)bh * 128 * 2048;

  // Q tile 128x128 staged through smem[0..16383] -> registers (64 q-rows/wave)
  stage_swz<128, 8>(Qh + (bhT + q0) * 128, 128, smem, tid);
  __syncthreads();
  const int mq0 = (w >> 1) * 64, nk0 = (w & 1) * 32;
  f16x8 qf[4][4];
  #pragma unroll
  for (int mt = 0; mt < 4; ++mt)
    #pragma unroll
    for (int kk = 0; kk < 4; ++kk)
      qf[mt][kk] = ld_frag(&smem[swz(mq0 + mt * 16 + lr, kk * 32 + lq * 8, 128, 15)]);
  __syncthreads();                            // Q reads done before K staging

  // prefetch first K/V tile into buffer 0
  stage_swz<128, 4>(Kh + (bhT + 0) * 128, 128, smem, tid);
  stage_swz<64, 4>(Vtb + 0, 2048, smem + 16384, tid);

  floatx4 oacc[2][8] = {};
  floatx4 den[2] = {};
  const ushort8_t onesu = {0x3C00, 0x3C00, 0x3C00, 0x3C00, 0x3C00, 0x3C00, 0x3C00, 0x3C00};
  const f16x8 ones = __builtin_bit_cast(f16x8, onesu);
  const float scale = 0.08838834764831845f;   // 1/sqrt(128)

  const int kend = q0 + 128;
  int buf = 0;
  for (int k0 = 0; k0 < kend; k0 += 64) {
    u16* Ks  = smem + buf * 8192;             // [64 k][128 d] swz cpr16
    u16* Vts = smem + 16384 + buf * 8192;     // [128 d][64 k] swz cpr8
    u16* Ps  = smem + 32768;                  // [128 q][64 k] swz cpr8
    __syncthreads();                          // B1: cur staging visible; prev PV fenced

    if (k0 + 64 < kend) {                     // issue prefetch of next tile (async)
      stage_swz<128, 4>(Kh + (bhT + k0 + 64) * 128, 128, smem + (buf ^ 1) * 8192, tid);
      stage_swz<64, 4>(Vtb + k0 + 64, 2048, smem + 16384 + (buf ^ 1) * 8192, tid);
    }

    // S = Q K^T : 64 q-rows x 32 keys per wave (kf read feeds 4 MFMAs)
    floatx4 s[4][2] = {};
    #pragma unroll
    for (int kk = 0; kk < 4; ++kk) {
      f16x8 kf[2];
      #pragma unroll
      for (int nt = 0; nt < 2; ++nt)
        kf[nt] = ld_frag(&Ks[swz(nk0 + nt * 16 + lr, kk * 32 + lq * 8, 128, 15)]);
      __builtin_amdgcn_s_setprio(1);
      #pragma unroll
      for (int mt = 0; mt < 4; ++mt)
        #pragma unroll
        for (int nt = 0; nt < 2; ++nt)
          s[mt][nt] = __builtin_amdgcn_mfma_f32_16x16x32_f16(qf[mt][kk], kf[nt], s[mt][nt], 0, 0, 0);
      __builtin_amdgcn_s_setprio(0);
    }

    // P = relu(S*scale + 0.1) -> Ps; causal mask only on diagonal-band tiles
    if (k0 < q0) {                            // interior: no mask needed
      #pragma unroll
      for (int mt = 0; mt < 4; ++mt) {
        const int rb = mq0 + mt * 16 + lq * 4;
        #pragma unroll
        for (int nt = 0; nt < 2; ++nt) {
          const int col = nk0 + nt * 16 + lr;
          #pragma unroll
          for (int r = 0; r < 4; ++r)
            Ps[swz(rb + r, col, 64, 7)] = f2h(fmaxf(s[mt][nt][r] * scale + 0.1f, 0.0f));
        }
      }
    } else {
      #pragma unroll
      for (int mt = 0; mt < 4; ++mt) {
        const int rb = mq0 + mt * 16 + lq * 4;
        #pragma unroll
        for (int nt = 0; nt < 2; ++nt) {
          const int col = nk0 + nt * 16 + lr;
          const int kg = k0 + col;
          #pragma unroll
          for (int r = 0; r < 4; ++r) {
            float v = fmaxf(s[mt][nt][r] * scale + 0.1f, 0.0f);
            v = (kg <= q0 + rb + r) ? v : 0.0f;
            Ps[swz(rb + r, col, 64, 7)] = f2h(v);
          }
        }
      }
    }
    __syncthreads();                          // B2: Ps visible

    // O += P @ Vt^T ; den += P @ 1   (wave w: q rows w*32..w*32+31, all d)
    #pragma unroll
    for (int kk = 0; kk < 2; ++kk) {
      f16x8 pf[2];
      #pragma unroll
      for (int mt = 0; mt < 2; ++mt)
        pf[mt] = ld_frag(&Ps[swz(w * 32 + mt * 16 + lr, kk * 32 + lq * 8, 64, 7)]);
      __builtin_amdgcn_s_setprio(1);
      #pragma unroll
      for (int mt = 0; mt < 2; ++mt)
        den[mt] = __builtin_amdgcn_mfma_f32_16x16x32_f16(pf[mt], ones, den[mt], 0, 0, 0);
      #pragma unroll
      for (int dt = 0; dt < 8; ++dt) {
        f16x8 vf = ld_frag(&Vts[swz(dt * 16 + lr, kk * 32 + lq * 8, 64, 7)]);
        #pragma unroll
        for (int mt = 0; mt < 2; ++mt)
          oacc[mt][dt] = __builtin_amdgcn_mfma_f32_16x16x32_f16(pf[mt], vf, oacc[mt][dt], 0, 0, 0);
      }
      __builtin_amdgcn_s_setprio(0);
    }
    buf ^= 1;
  }

  // epilogue: Ob [B*T, 2048] fp16 (row = b*2048 + t, col = h*128 + d)
  const int b = bh >> 4, h = bh & 15;
  #pragma unroll
  for (int mt = 0; mt < 2; ++mt) {
    #pragma unroll
    for (int r = 0; r < 4; ++r) {
      const int qrow = w * 32 + mt * 16 + lq * 4 + r;
      const float inv = 1.0f / (den[mt][r] + 1e-6f);
      u16* dst = Ob + ((size_t)(b * 2048 + q0 + qrow)) * 2048 + h * 128;
      #pragma unroll
      for (int dt = 0; dt < 8; ++dt)
        dst[dt * 16 + lr] = f2h(oacc[mt][dt][r] * inv);
    }
  }
}

// ---------------------------------------------------------------- launch
extern "C" void kernel_launch(void* const* d_in, const int* in_sizes, int n_in,
                              void* d_out, int out_size, void* d_ws, size_t ws_size,
                              hipStream_t stream) {
  const float* x  = (const float*)d_in[0];
  const float* Wq = (const float*)d_in[1];
  const float* Wk = (const float*)d_in[2];
  const float* Wv = (const float*)d_in[3];
  const float* Wo = (const float*)d_in[4];
  float* out = (float*)d_out;

  const size_t MB = 1024 * 1024;
  char* ws = (char*)d_ws;
  // workspace (96 MB). Ob aliases xb (dead after QKV GEMM).
  u16* xb  = (u16*)(ws);               // 16 MB [4096,2048] fp16 (later Ob)
  u16* Wqb = (u16*)(ws + 16 * MB);     //  8 MB each
  u16* Wkb = (u16*)(ws + 24 * MB);
  u16* Wvb = (u16*)(ws + 32 * MB);
  u16* Wob = (u16*)(ws + 40 * MB);
  u16* Qh  = (u16*)(ws + 48 * MB);     // 16 MB [BH,T,128]
  u16* Kh  = (u16*)(ws + 64 * MB);     // 16 MB
  u16* Vt  = (u16*)(ws + 80 * MB);     // 16 MB [BH,128,T]
  u16* Ob  = xb;

  // all converts in one launch: (2^21 + 4*2^20) float4 groups / 256 threads
  convert_all<<<24576, 256, 0, stream>>>(x, Wq, Wk, Wv, Wo, xb, Wqb, Wkb, Wvb, Wob);

  // fused QKV: N = 6144; V written pre-transposed. 768 blocks (32x24).
  gemm_wide<3><<<dim3(768), 256, 0, stream>>>(
      xb, Wqb, Wkb, Wvb, (void*)Qh, (void*)Kh, (void*)Vt, 4096, 6144, 2048);

  attn_kernel<<<dim3(32, 16), 256, 0, stream>>>(Qh, Kh, Vt, Ob);

  // out projection: 256 blocks (32x8).
  gemm_wide<1><<<dim3(256), 256, 0, stream>>>(
      Ob, Wob, nullptr, nullptr, (void*)out, nullptr, nullptr, 4096, 2048, 2048);
}

// Round 3
// 351.705 us; speedup vs baseline: 1.0077x; 1.0026x over previous
//
#include <hip/hip_runtime.h>
#include <stdint.h>

// GhostAttention on MI355X (gfx950). B=2, T=2048, C=2048, H=16, hd=128.
// All-fp16 pipeline: convert (single launch) -> fused QKV GEMM (8-phase 256^2)
// -> causal relu-attention (linear normalizer) -> out GEMM (R5 128^2, fp32).
//
// R8: R6/R7 post-mortems: 128-reg accumulators pin ANY config at 2 waves/SIMD,
// so multi-block TLP cannot cover the stage->sync->compute drain; overlap must
// come from the in-block schedule. This round ports the verified 8-phase 256^2
// template for QKV: 8 waves (2x4) of 128x64 (AI 2.67), 2-buffer 128 KB LDS,
// per-phase {ds_read || 1 half-tile gload_lds; barrier; lgkm(0); setprio(1);
// 16 MFMA; setprio(0); barrier}, counted vmcnt(2) once per K-tile (never 0 in
// steady state). Staging schedule per tile u: B-h1(u+1), A-h0(u+1), A-h1(u+1),
// B-h0(u+2) - clobber-free (each region's last reader completes before the
// end-of-phase barrier preceding its overwrite). Out-proj reverts to R5's
// proven gemm_bt (full packing beats a half-idle 256^2 grid of 128 blocks).

typedef unsigned short u16;
typedef _Float16 f16x8 __attribute__((ext_vector_type(8)));
typedef float floatx4 __attribute__((ext_vector_type(4)));
typedef unsigned short ushort8_t __attribute__((ext_vector_type(8)));

__device__ __forceinline__ u16 f2h(float f) {
  _Float16 h = (_Float16)f;                  // v_cvt_f16_f32, RNE
  return __builtin_bit_cast(u16, h);
}
__device__ __forceinline__ f16x8 ld_frag(const u16* p) {
  return __builtin_bit_cast(f16x8, *(const ushort8_t*)p);
}

// XOR-swizzled LDS offset: row length R elems (R%8==0), cprMask = R/8-1.
__device__ __forceinline__ int swz(int row, int col, int R, int cprMask) {
  int chunk = ((col >> 3) ^ row) & cprMask;
  return row * R + chunk * 8 + (col & 7);
}

__device__ __forceinline__ void async_copy16(const void* g, void* l) {
  __builtin_amdgcn_global_load_lds(
      (const __attribute__((address_space(1))) void*)g,
      (__attribute__((address_space(3))) void*)l, 16, 0, 0);
}

// Stage instructions [I0,I1) of a (rows x R fp16) tile (row stride grs) into
// swizzled LDS; NTHR threads, 16B per thread per instruction.
template<int R, int I0, int I1, int NTHR>
__device__ __forceinline__ void stage_part(const u16* g, size_t grs, u16* lds, int tid) {
  constexpr int CPR = R / 8;
  #pragma unroll
  for (int i = I0; i < I1; ++i) {
    int f = tid + i * NTHR;
    int row = f / CPR;
    int sc = f & (CPR - 1);
    int c = sc ^ (row & (CPR - 1));
    async_copy16(g + (size_t)row * grs + c * 8, (char*)lds + f * 16);
  }
}

// 256-thread version.
template<int R, int NINST>
__device__ __forceinline__ void stage_swz(const u16* g, size_t grs, u16* lds, int tid) {
  stage_part<R, 0, NINST, 256>(g, grs, lds, tid);
}

__device__ __forceinline__ void bar_() { asm volatile("s_barrier" ::: "memory"); }
__device__ __forceinline__ void lgkm0_() { asm volatile("s_waitcnt lgkmcnt(0)" ::: "memory"); }

// ---------------------------------------------------------------- converts
// One launch for all five fp32->fp16 conversions. Regions in float4 groups:
// x = 2^21 groups, each W = 2^20 groups.
__global__ void convert_all(const float* __restrict__ x,
                            const float* __restrict__ Wq, const float* __restrict__ Wk,
                            const float* __restrict__ Wv, const float* __restrict__ Wo,
                            u16* __restrict__ xb, u16* __restrict__ wqb, u16* __restrict__ wkb,
                            u16* __restrict__ wvb, u16* __restrict__ wob) {
  const int gi = blockIdx.x * 256 + threadIdx.x;   // float4-group index
  const float* src;
  u16* dst;
  int off;
  if (gi < (1 << 21)) {
    src = x; dst = xb; off = gi;
  } else {
    const int j = gi - (1 << 21);
    const int wsel = j >> 20;
    off = j & ((1 << 20) - 1);
    src = (wsel == 0) ? Wq : (wsel == 1) ? Wk : (wsel == 2) ? Wv : Wo;
    dst = (wsel == 0) ? wqb : (wsel == 1) ? wkb : (wsel == 2) ? wvb : wob;
  }
  float4 v = ((const float4*)src)[off];
  ushort4 o;
  o.x = f2h(v.x); o.y = f2h(v.y); o.z = f2h(v.z); o.w = f2h(v.w);
  ((ushort4*)dst)[off] = o;
}

// ------------------------------------------------- QKV GEMM: 8-phase 256^2
// C = A[M,K] @ B[N,K]^T, fp16 in, fp32 accum. BM=BN=256, BK=64, 512 threads
// (8 waves 2x4, wave tile 128x64). LDS: 2 x (A 256x64 | B 256x64) = 128 KB.
// Fused QKV: N=6144; sel = bn0>>11 -> Q (C0) / K (C1) head-major [B,H,T,128];
// V (C2) written TRANSPOSED [B,H,128,T] via full-smem 256x256 LDS pass.
__global__ __launch_bounds__(512, 2) void gemm256(
    const u16* __restrict__ A,
    const u16* __restrict__ B0, const u16* __restrict__ B1, const u16* __restrict__ B2,
    void* __restrict__ C0, void* __restrict__ C1, void* __restrict__ C2,
    const int M, const int N, const int K)
{
  __shared__ __align__(16) u16 smem[2 * 32768];   // 128 KB
  const int tid = threadIdx.x;
  const int w = tid >> 6, lane = tid & 63, lr = lane & 15, lq = lane >> 4;
  const int wr = w >> 2, wc = w & 3;              // 2(m) x 4(n) wave grid

  // XCD-bijective swizzle (nwg=384, %8==0) + 8-row m-supertile.
  const int nbx = N >> 8, nby = M >> 8;           // 24 x 16
  const int nwg = nbx * nby;
  int wg = blockIdx.x;
  wg = (wg & 7) * (nwg >> 3) + (wg >> 3);
  const int sg = nbx * 8;
  const int rg = wg % sg;
  const int by = (wg / sg) * 8 + (rg & 7);
  const int bx = rg >> 3;
  const int bn0 = bx << 8, bm0 = by << 8;

  const u16* Ab = A + (size_t)bm0 * K;
  const int sel = bn0 >> 11;                      // 0:Q 1:K 2:V
  const u16* Bsel = (sel == 0) ? B0 : (sel == 1) ? B1 : B2;
  const u16* Bb = Bsel + (size_t)(bn0 & 2047) * K;

  floatx4 acc[8][4] = {};                         // 128 accum regs (AGPR)
  const int NT = K >> 6;                          // 32 K-tiles

  // prologue: tile0 fully + B-h0(1); leave B-h0(1) outstanding (steady state)
  stage_part<64, 0, 2, 512>(Ab,            K, smem,                   tid); // A-h0(0)
  stage_part<64, 0, 2, 512>(Ab + 128 * K,  K, smem + 8192,            tid); // A-h1(0)
  stage_part<64, 0, 2, 512>(Bb,            K, smem + 16384,           tid); // B-h0(0)
  stage_part<64, 0, 2, 512>(Bb + 128 * K,  K, smem + 16384 + 8192,    tid); // B-h1(0)
  stage_part<64, 0, 2, 512>(Bb + 64,       K, smem + 32768 + 16384,   tid); // B-h0(1)
  asm volatile("s_waitcnt vmcnt(2)" ::: "memory");
  bar_();

  for (int u = 0; u < NT; ++u) {
    const u16* As = smem + (u & 1) * 32768;
    const u16* Bs = As + 16384;
    u16* nb = smem + ((u + 1) & 1) * 32768;       // buffer of tile u+1
    u16* cb = smem + (u & 1) * 32768;             // buffer of tile u (-> u+2)
    const bool s1 = (u + 1) < NT, s2 = (u + 2) < NT;
    f16x8 af[4], bf[4];

    // ---- P1: af[m0-3]@kk0 + bf@kk0 (8 reads); stage B-h1(u+1)
    #pragma unroll
    for (int i = 0; i < 4; ++i)
      af[i] = ld_frag(&As[swz(wr * 128 + i * 16 + lr, lq * 8, 64, 7)]);
    #pragma unroll
    for (int i = 0; i < 4; ++i)
      bf[i] = ld_frag(&Bs[swz(wc * 64 + i * 16 + lr, lq * 8, 64, 7)]);
    if (s1) stage_part<64, 0, 2, 512>(Bb + (size_t)128 * K + (u + 1) * 64, K,
                                      nb + 16384 + 8192, tid);
    bar_(); lgkm0_();
    __builtin_amdgcn_s_setprio(1);
    #pragma unroll
    for (int mt = 0; mt < 4; ++mt)
      #pragma unroll
      for (int nt = 0; nt < 4; ++nt)
        acc[mt][nt] = __builtin_amdgcn_mfma_f32_16x16x32_f16(af[mt], bf[nt], acc[mt][nt], 0, 0, 0);
    __builtin_amdgcn_s_setprio(0);
    bar_();

    // ---- P2: af[m4-7]@kk0 (4 reads, bf kept); stage A-h0(u+1)
    #pragma unroll
    for (int i = 0; i < 4; ++i)
      af[i] = ld_frag(&As[swz(wr * 128 + 64 + i * 16 + lr, lq * 8, 64, 7)]);
    if (s1) stage_part<64, 0, 2, 512>(Ab + (u + 1) * 64, K, nb, tid);
    bar_(); lgkm0_();
    __builtin_amdgcn_s_setprio(1);
    #pragma unroll
    for (int mt = 0; mt < 4; ++mt)
      #pragma unroll
      for (int nt = 0; nt < 4; ++nt)
        acc[4 + mt][nt] = __builtin_amdgcn_mfma_f32_16x16x32_f16(af[mt], bf[nt], acc[4 + mt][nt], 0, 0, 0);
    __builtin_amdgcn_s_setprio(0);
    bar_();

    // ---- P3: af[m0-3]@kk1 + bf@kk1 (8 reads); stage A-h1(u+1)
    #pragma unroll
    for (int i = 0; i < 4; ++i)
      af[i] = ld_frag(&As[swz(wr * 128 + i * 16 + lr, 32 + lq * 8, 64, 7)]);
    #pragma unroll
    for (int i = 0; i < 4; ++i)
      bf[i] = ld_frag(&Bs[swz(wc * 64 + i * 16 + lr, 32 + lq * 8, 64, 7)]);
    if (s1) stage_part<64, 0, 2, 512>(Ab + (size_t)128 * K + (u + 1) * 64, K,
                                      nb + 8192, tid);
    bar_(); lgkm0_();
    __builtin_amdgcn_s_setprio(1);
    #pragma unroll
    for (int mt = 0; mt < 4; ++mt)
      #pragma unroll
      for (int nt = 0; nt < 4; ++nt)
        acc[mt][nt] = __builtin_amdgcn_mfma_f32_16x16x32_f16(af[mt], bf[nt], acc[mt][nt], 0, 0, 0);
    __builtin_amdgcn_s_setprio(0);
    bar_();

    // ---- P4: af[m4-7]@kk1 (4 reads); stage B-h0(u+2); counted vmcnt
    #pragma unroll
    for (int i = 0; i < 4; ++i)
      af[i] = ld_frag(&As[swz(wr * 128 + 64 + i * 16 + lr, 32 + lq * 8, 64, 7)]);
    if (s2) stage_part<64, 0, 2, 512>(Bb + (size_t)(u + 2) * 64, K, cb + 16384, tid);
    bar_(); lgkm0_();
    __builtin_amdgcn_s_setprio(1);
    #pragma unroll
    for (int mt = 0; mt < 4; ++mt)
      #pragma unroll
      for (int nt = 0; nt < 4; ++nt)
        acc[4 + mt][nt] = __builtin_amdgcn_mfma_f32_16x16x32_f16(af[mt], bf[nt], acc[4 + mt][nt], 0, 0, 0);
    __builtin_amdgcn_s_setprio(0);
    if (s2) asm volatile("s_waitcnt vmcnt(2)" ::: "memory");
    else    asm volatile("s_waitcnt vmcnt(0)" ::: "memory");
    bar_();
  }

  // epilogue: C/D layout col=lane&15, row=(lane>>4)*4+reg
  if (sel == 2) {
    // V: transpose 256(t) x 256(d, 2 heads) through full smem, write
    // Vt [BH,128,T] coalesced. All loop barriers passed; smem reusable.
    #pragma unroll
    for (int mh = 0; mh < 2; ++mh) {
      #pragma unroll
      for (int mt = 0; mt < 4; ++mt) {
        #pragma unroll
        for (int nt = 0; nt < 4; ++nt) {
          #pragma unroll
          for (int r = 0; r < 4; ++r) {
            const int tl = wr * 128 + mh * 64 + mt * 16 + lq * 4 + r;  // t 0..255
            const int dl = wc * 64 + nt * 16 + lr;                     // d 0..255
            smem[swz(dl, tl, 256, 31)] = f2h(acc[mh * 4 + mt][nt][r]);
          }
        }
      }
    }
    __syncthreads();
    const int bb = bm0 >> 11, t0 = bm0 & 2047;
    const int n0 = bn0 & 2047;
    #pragma unroll
    for (int i = 0; i < 16; ++i) {
      const int f = tid + i * 512;             // chunk id 0..8191
      const int row = f >> 5;                  // local d (0..255)
      const int cc = f & 31;                   // stored chunk
      const int c = cc ^ (row & 31);           // logical t-chunk
      ushort8_t v = *(const ushort8_t*)&smem[row * 256 + cc * 8];
      const int h = (n0 + row) >> 7, d = (n0 + row) & 127;
      *(ushort8_t*)((u16*)C2 + ((size_t)(bb * 16 + h) * 128 + d) * 2048 + t0 + c * 8) = v;
    }
  } else {
    u16* Cs = (sel == 0) ? (u16*)C0 : (u16*)C1;
    #pragma unroll
    for (int mh = 0; mh < 2; ++mh) {
      #pragma unroll
      for (int mt = 0; mt < 4; ++mt) {
        #pragma unroll
        for (int nt = 0; nt < 4; ++nt) {
          #pragma unroll
          for (int r = 0; r < 4; ++r) {
            const int m = bm0 + wr * 128 + mh * 64 + mt * 16 + lq * 4 + r;
            const int nn = (bn0 & 2047) + wc * 64 + nt * 16 + lr;
            const int bb = m >> 11, tt = m & 2047, h = nn >> 7, d = nn & 127;
            const size_t idx = (((size_t)(bb * 16 + h) * 2048) + tt) * 128 + d;
            Cs[idx] = f2h(acc[mh * 4 + mt][nt][r]);
          }
        }
      }
    }
  }
}

// ------------------------------------------------- out-proj GEMM (R5 128^2)
// C0[M,N] fp32 = A[M,K] @ B[N,K]^T. 128x128 tile, BK=64, 4 waves 2x2,
// single-buffer stage->sync->compute; overlap from 3 blocks/CU (low regs).
__global__ __launch_bounds__(256, 3) void gemm_bt(
    const u16* __restrict__ A, const u16* __restrict__ B0,
    float* __restrict__ C0, const int M, const int N, const int K)
{
  __shared__ __align__(16) u16 smem[128 * 128];  // 32 KB: As|Bs
  u16* As = smem;
  u16* Bs = smem + 128 * 64;
  const int tid = threadIdx.x;
  const int w = tid >> 6, lane = tid & 63, lr = lane & 15, lq = lane >> 4;
  const int bn0 = blockIdx.x * 128, bm0 = blockIdx.y * 128;
  const int wm = (w >> 1) * 64, wn = (w & 1) * 64;
  floatx4 acc[4][4] = {};
  const u16* Ab = A + (size_t)bm0 * K;
  const u16* Bb = B0 + (size_t)bn0 * K;

  for (int k0 = 0; k0 < K; k0 += 64) {
    __syncthreads();
    stage_swz<64, 4>(Ab + k0, K, As, tid);
    stage_swz<64, 4>(Bb + k0, K, Bs, tid);
    __syncthreads();
    #pragma unroll
    for (int kk = 0; kk < 2; ++kk) {
      f16x8 af[4], bfr[4];
      #pragma unroll
      for (int t = 0; t < 4; ++t) {
        af[t]  = ld_frag(&As[swz(wm + t * 16 + lr, kk * 32 + lq * 8, 64, 7)]);
        bfr[t] = ld_frag(&Bs[swz(wn + t * 16 + lr, kk * 32 + lq * 8, 64, 7)]);
      }
      #pragma unroll
      for (int mt = 0; mt < 4; ++mt)
        #pragma unroll
        for (int nt = 0; nt < 4; ++nt)
          acc[mt][nt] = __builtin_amdgcn_mfma_f32_16x16x32_f16(af[mt], bfr[nt], acc[mt][nt], 0, 0, 0);
    }
  }

  #pragma unroll
  for (int mt = 0; mt < 4; ++mt) {
    #pragma unroll
    for (int nt = 0; nt < 4; ++nt) {
      #pragma unroll
      for (int r = 0; r < 4; ++r) {
        const int m = bm0 + wm + mt * 16 + lq * 4 + r;
        const int n = bn0 + wn + nt * 16 + lr;
        C0[(size_t)m * N + n] = acc[mt][nt][r];
      }
    }
  }
}

// ---------------------------------------------------------------- attention
// Block: one (bh, 128-row q-tile). k-tiles of 64, K/V double-buffered:
// per iter [B1: staging visible + prev PV fenced; issue prefetch; QK; P-write;
// B2: Ps visible (drains prefetch after QK overlap); PV]. 2 barriers/iter.
// QK wave-split 64q x 32k; setprio(1) around MFMA clusters (T5).
// LDS 80 KB: Ks0|Ks1|Vts0|Vts1|Ps -> 2 blocks/CU.
__global__ __launch_bounds__(256, 2) void attn_kernel(
    const u16* __restrict__ Qh, const u16* __restrict__ Kh,
    const u16* __restrict__ Vt, u16* __restrict__ Ob)
{
  __shared__ __align__(16) u16 smem[40960];   // 80 KB
  const int tid = threadIdx.x;
  const int w = tid >> 6, lane = tid & 63, lr = lane & 15, lq = lane >> 4;
  const int bh = blockIdx.x;
  const int y = blockIdx.y;
  // complementary interleave: blocks y and y+8 have qt summing to 15 ->
  // uniform k-iter load across CUs
  const int qt = (y < 8) ? (15 - y) : (y - 8);
  const int q0 = qt * 128;
  const size_t bhT = (size_t)bh * 2048;
  const u16* Vtb = Vt + (size_t)bh * 128 * 2048;

  // Q tile 128x128 staged through smem[0..16383] -> registers (64 q-rows/wave)
  stage_swz<128, 8>(Qh + (bhT + q0) * 128, 128, smem, tid);
  __syncthreads();
  const int mq0 = (w >> 1) * 64, nk0 = (w & 1) * 32;
  f16x8 qf[4][4];
  #pragma unroll
  for (int mt = 0; mt < 4; ++mt)
    #pragma unroll
    for (int kk = 0; kk < 4; ++kk)
      qf[mt][kk] = ld_frag(&smem[swz(mq0 + mt * 16 + lr, kk * 32 + lq * 8, 128, 15)]);
  __syncthreads();                            // Q reads done before K staging

  // prefetch first K/V tile into buffer 0
  stage_swz<128, 4>(Kh + (bhT + 0) * 128, 128, smem, tid);
  stage_swz<64, 4>(Vtb + 0, 2048, smem + 16384, tid);

  floatx4 oacc[2][8] = {};
  floatx4 den[2] = {};
  const ushort8_t onesu = {0x3C00, 0x3C00, 0x3C00, 0x3C00, 0x3C00, 0x3C00, 0x3C00, 0x3C00};
  const f16x8 ones = __builtin_bit_cast(f16x8, onesu);
  const float scale = 0.08838834764831845f;   // 1/sqrt(128)

  const int kend = q0 + 128;
  int buf = 0;
  for (int k0 = 0; k0 < kend; k0 += 64) {
    u16* Ks  = smem + buf * 8192;             // [64 k][128 d] swz cpr16
    u16* Vts = smem + 16384 + buf * 8192;     // [128 d][64 k] swz cpr8
    u16* Ps  = smem + 32768;                  // [128 q][64 k] swz cpr8
    __syncthreads();                          // B1: cur staging visible; prev PV fenced

    if (k0 + 64 < kend) {                     // issue prefetch of next tile (async)
      stage_swz<128, 4>(Kh + (bhT + k0 + 64) * 128, 128, smem + (buf ^ 1) * 8192, tid);
      stage_swz<64, 4>(Vtb + k0 + 64, 2048, smem + 16384 + (buf ^ 1) * 8192, tid);
    }

    // S = Q K^T : 64 q-rows x 32 keys per wave (kf read feeds 4 MFMAs)
    floatx4 s[4][2] = {};
    #pragma unroll
    for (int kk = 0; kk < 4; ++kk) {
      f16x8 kf[2];
      #pragma unroll
      for (int nt = 0; nt < 2; ++nt)
        kf[nt] = ld_frag(&Ks[swz(nk0 + nt * 16 + lr, kk * 32 + lq * 8, 128, 15)]);
      __builtin_amdgcn_s_setprio(1);
      #pragma unroll
      for (int mt = 0; mt < 4; ++mt)
        #pragma unroll
        for (int nt = 0; nt < 2; ++nt)
          s[mt][nt] = __builtin_amdgcn_mfma_f32_16x16x32_f16(qf[mt][kk], kf[nt], s[mt][nt], 0, 0, 0);
      __builtin_amdgcn_s_setprio(0);
    }

    // P = relu(S*scale + 0.1) -> Ps; causal mask only on diagonal-band tiles
    if (k0 < q0) {                            // interior: no mask needed
      #pragma unroll
      for (int mt = 0; mt < 4; ++mt) {
        const int rb = mq0 + mt * 16 + lq * 4;
        #pragma unroll
        for (int nt = 0; nt < 2; ++nt) {
          const int col = nk0 + nt * 16 + lr;
          #pragma unroll
          for (int r = 0; r < 4; ++r)
            Ps[swz(rb + r, col, 64, 7)] = f2h(fmaxf(s[mt][nt][r] * scale + 0.1f, 0.0f));
        }
      }
    } else {
      #pragma unroll
      for (int mt = 0; mt < 4; ++mt) {
        const int rb = mq0 + mt * 16 + lq * 4;
        #pragma unroll
        for (int nt = 0; nt < 2; ++nt) {
          const int col = nk0 + nt * 16 + lr;
          const int kg = k0 + col;
          #pragma unroll
          for (int r = 0; r < 4; ++r) {
            float v = fmaxf(s[mt][nt][r] * scale + 0.1f, 0.0f);
            v = (kg <= q0 + rb + r) ? v : 0.0f;
            Ps[swz(rb + r, col, 64, 7)] = f2h(v);
          }
        }
      }
    }
    __syncthreads();                          // B2: Ps visible

    // O += P @ Vt^T ; den += P @ 1   (wave w: q rows w*32..w*32+31, all d)
    #pragma unroll
    for (int kk = 0; kk < 2; ++kk) {
      f16x8 pf[2];
      #pragma unroll
      for (int mt = 0; mt < 2; ++mt)
        pf[mt] = ld_frag(&Ps[swz(w * 32 + mt * 16 + lr, kk * 32 + lq * 8, 64, 7)]);
      __builtin_amdgcn_s_setprio(1);
      #pragma unroll
      for (int mt = 0; mt < 2; ++mt)
        den[mt] = __builtin_amdgcn_mfma_f32_16x16x32_f16(pf[mt], ones, den[mt], 0, 0, 0);
      #pragma unroll
      for (int dt = 0; dt < 8; ++dt) {
        f16x8 vf = ld_frag(&Vts[swz(dt * 16 + lr, kk * 32 + lq * 8, 64, 7)]);
        #pragma unroll
        for (int mt = 0; mt < 2; ++mt)
          oacc[mt][dt] = __builtin_amdgcn_mfma_f32_16x16x32_f16(pf[mt], vf, oacc[mt][dt], 0, 0, 0);
      }
      __builtin_amdgcn_s_setprio(0);
    }
    buf ^= 1;
  }

  // epilogue: Ob [B*T, 2048] fp16 (row = b*2048 + t, col = h*128 + d)
  const int b = bh >> 4, h = bh & 15;
  #pragma unroll
  for (int mt = 0; mt < 2; ++mt) {
    #pragma unroll
    for (int r = 0; r < 4; ++r) {
      const int qrow = w * 32 + mt * 16 + lq * 4 + r;
      const float inv = 1.0f / (den[mt][r] + 1e-6f);
      u16* dst = Ob + ((size_t)(b * 2048 + q0 + qrow)) * 2048 + h * 128;
      #pragma unroll
      for (int dt = 0; dt < 8; ++dt)
        dst[dt * 16 + lr] = f2h(oacc[mt][dt][r] * inv);
    }
  }
}

// ---------------------------------------------------------------- launch
extern "C" void kernel_launch(void* const* d_in, const int* in_sizes, int n_in,
                              void* d_out, int out_size, void* d_ws, size_t ws_size,
                              hipStream_t stream) {
  const float* x  = (const float*)d_in[0];
  const float* Wq = (const float*)d_in[1];
  const float* Wk = (const float*)d_in[2];
  const float* Wv = (const float*)d_in[3];
  const float* Wo = (const float*)d_in[4];
  float* out = (float*)d_out;

  const size_t MB = 1024 * 1024;
  char* ws = (char*)d_ws;
  // workspace (96 MB). Ob aliases xb (dead after QKV GEMM).
  u16* xb  = (u16*)(ws);               // 16 MB [4096,2048] fp16 (later Ob)
  u16* Wqb = (u16*)(ws + 16 * MB);     //  8 MB each
  u16* Wkb = (u16*)(ws + 24 * MB);
  u16* Wvb = (u16*)(ws + 32 * MB);
  u16* Wob = (u16*)(ws + 40 * MB);
  u16* Qh  = (u16*)(ws + 48 * MB);     // 16 MB [BH,T,128]
  u16* Kh  = (u16*)(ws + 64 * MB);     // 16 MB
  u16* Vt  = (u16*)(ws + 80 * MB);     // 16 MB [BH,128,T]
  u16* Ob  = xb;

  // all converts in one launch: (2^21 + 4*2^20) float4 groups / 256 threads
  convert_all<<<24576, 256, 0, stream>>>(x, Wq, Wk, Wv, Wo, xb, Wqb, Wkb, Wvb, Wob);

  // fused QKV: 8-phase 256^2, N = 6144; V written pre-transposed. 384 blocks.
  gemm256<<<dim3(384), 512, 0, stream>>>(
      xb, Wqb, Wkb, Wvb, (void*)Qh, (void*)Kh, (void*)Vt, 4096, 6144, 2048);

  attn_kernel<<<dim3(32, 16), 256, 0, stream>>>(Qh, Kh, Vt, Ob);

  // out projection: R5 128^2 structure, full grid packing.
  gemm_bt<<<dim3(2048 / 128, 4096 / 128), 256, 0, stream>>>(
      Ob, Wob, (float*)out, 4096, 2048, 2048);
}